// Round 3
// baseline (829.778 us; speedup 1.0000x reference)
//
#include <hip/hip_runtime.h>
#include <math.h>

#define D_MODEL 1024
#define NUM_SEGS 64
#define CT 16                          // tokens per wave-chunk
#define TOTAL_TOKENS 131072
#define MAXC (TOTAL_TOKENS / CT + NUM_SEGS)   // 8256, divisible by 4
#define WPB 4                          // waves per block

// ---------------------------------------------------------------------------
// Setup: one block. Builds chunk prefix sums cuc[65] and per-chunk (t0,t1)
// table so pass1 needs no LDS, no barriers, no per-block prefix scan.
// ---------------------------------------------------------------------------
__global__ __launch_bounds__(256) void seg_pool_setup(
    const int* __restrict__ cu, int* __restrict__ cuc_out,
    int2* __restrict__ ctab)
{
    __shared__ int s_cu[NUM_SEGS + 1];
    __shared__ int s_cuc[NUM_SEGS + 1];
    const int tid = threadIdx.x;
    if (tid <= NUM_SEGS) s_cu[tid] = cu[tid];
    __syncthreads();
    if (tid == 0) {
        int acc = 0; s_cuc[0] = 0;
        for (int s = 0; s < NUM_SEGS; ++s) {
            acc += (s_cu[s + 1] - s_cu[s] + CT - 1) / CT;
            s_cuc[s + 1] = acc;
        }
    }
    __syncthreads();
    if (tid <= NUM_SEGS) cuc_out[tid] = s_cuc[tid];
    const int total = s_cuc[NUM_SEGS];
    for (int i = tid; i < MAXC; i += 256) {
        int2 e;
        if (i >= total) { e.x = 0; e.y = 0; }          // empty chunk
        else {
            int lo = 0, hi = NUM_SEGS;
            while (hi - lo > 1) {
                int mid = (lo + hi) >> 1;
                if (s_cuc[mid] <= i) lo = mid; else hi = mid;
            }
            e.x = s_cu[lo] + (i - s_cuc[lo]) * CT;
            e.y = min(e.x + CT, s_cu[lo + 1]);
        }
        ctab[i] = e;
    }
}

// ---------------------------------------------------------------------------
// Pass 1: one wave per chunk (<=16 tokens), online softmax accumulate.
// Barrier-free, LDS-free. Lane l holds dims {l*4 + k*256 .. +3}, k=0..3.
// ---------------------------------------------------------------------------
__global__ __launch_bounds__(256) void seg_pool_pass1(
    const float* __restrict__ x, const int2* __restrict__ ctab,
    const float* __restrict__ W, const float* __restrict__ bias_p,
    float* __restrict__ m_arr, float* __restrict__ l_arr,
    float* __restrict__ o_arr)
{
    const int wave = threadIdx.x >> 6;
    const int lane = threadIdx.x & 63;
    const int chunk = blockIdx.x * WPB + wave;
    const int2 r = ctab[chunk];           // broadcast load, cached

    float4 w4[4];
#pragma unroll
    for (int k = 0; k < 4; ++k)
        w4[k] = *(const float4*)(W + k * 256 + lane * 4);
    const float bias = bias_p[0];

    float m = -INFINITY;
    float lsum = 0.0f;
    float4 o[4];
#pragma unroll
    for (int k = 0; k < 4; ++k) o[k] = make_float4(0.f, 0.f, 0.f, 0.f);

    for (int t = r.x; t < r.y; ++t) {
        const float* row = x + (size_t)t * D_MODEL;
        float4 v[4];
#pragma unroll
        for (int k = 0; k < 4; ++k)
            v[k] = *(const float4*)(row + k * 256 + lane * 4);

        float dot = 0.0f;
#pragma unroll
        for (int k = 0; k < 4; ++k) {
            dot += v[k].x * w4[k].x; dot += v[k].y * w4[k].y;
            dot += v[k].z * w4[k].z; dot += v[k].w * w4[k].w;
        }
#pragma unroll
        for (int off = 32; off > 0; off >>= 1)
            dot += __shfl_xor(dot, off, 64);

        const float sc = dot + bias;
        const float mnew = fmaxf(m, sc);
        const float scale = __expf(m - mnew);   // first iter: exp(-inf)=0
        const float p = __expf(sc - mnew);
        lsum = lsum * scale + p;
#pragma unroll
        for (int k = 0; k < 4; ++k) {
            o[k].x = o[k].x * scale + p * v[k].x;
            o[k].y = o[k].y * scale + p * v[k].y;
            o[k].z = o[k].z * scale + p * v[k].z;
            o[k].w = o[k].w * scale + p * v[k].w;
        }
        m = mnew;
    }

    // empty chunks (beyond total) write m=-inf, l=0, o=0; never read by pass2
    if (lane == 0) { m_arr[chunk] = m; l_arr[chunk] = lsum; }
    float* op = o_arr + (size_t)chunk * D_MODEL;
#pragma unroll
    for (int k = 0; k < 4; ++k)
        *(float4*)(op + k * 256 + lane * 4) = o[k];
}

// ---------------------------------------------------------------------------
// Pass 2: grid (64 segs, 4 D-slices); thread owns one output dim.
// out[seg][d] = sum_c e^{m_c-m*} o_c[d] / sum_c e^{m_c-m*} l_c
// ---------------------------------------------------------------------------
__global__ __launch_bounds__(256) void seg_pool_pass2(
    const int* __restrict__ cuc, const float* __restrict__ m_arr,
    const float* __restrict__ l_arr, const float* __restrict__ o_arr,
    float* __restrict__ out)
{
    const int seg = blockIdx.x;
    const int c0 = cuc[seg], c1 = cuc[seg + 1];
    const int d = blockIdx.y * 256 + threadIdx.x;

    float mstar = -INFINITY;
    for (int c = c0; c < c1; ++c) mstar = fmaxf(mstar, m_arr[c]);

    float acc = 0.0f, lstar = 0.0f;
#pragma unroll 4
    for (int c = c0; c < c1; ++c) {
        const float coef = __expf(m_arr[c] - mstar);
        lstar += coef * l_arr[c];
        acc += coef * o_arr[(size_t)c * D_MODEL + d];
    }
    out[(size_t)seg * D_MODEL + d] = acc / lstar;
}

extern "C" void kernel_launch(void* const* d_in, const int* in_sizes, int n_in,
                              void* d_out, int out_size, void* d_ws, size_t ws_size,
                              hipStream_t stream) {
    const float* x  = (const float*)d_in[0];
    const int*   cu = (const int*)d_in[1];
    const float* W  = (const float*)d_in[2];
    const float* b  = (const float*)d_in[3];
    float* out = (float*)d_out;

    // ws layout (bytes): ctab int2[MAXC] | cuc int[65] pad to 16 | m f32[MAXC]
    //                    | l f32[MAXC] | o f32[MAXC*1024]
    char* w = (char*)d_ws;
    int2* ctab  = (int2*)w;                       w += (size_t)MAXC * 8;   // 66048
    int*  cuc   = (int*)w;                        w += 80 * 4;             // 65 ints + pad
    float* m_arr = (float*)w;                     w += (size_t)MAXC * 4;
    float* l_arr = (float*)w;                     w += (size_t)MAXC * 4;
    float* o_arr = (float*)w;

    seg_pool_setup<<<dim3(1), dim3(256), 0, stream>>>(cu, cuc, ctab);
    seg_pool_pass1<<<dim3(MAXC / WPB), dim3(256), 0, stream>>>(
        x, ctab, W, b, m_arr, l_arr, o_arr);
    seg_pool_pass2<<<dim3(NUM_SEGS, 4), dim3(256), 0, stream>>>(
        cuc, m_arr, l_arr, o_arr, out);
}